// Round 1
// baseline (683.751 us; speedup 1.0000x reference)
//
#include <hip/hip_runtime.h>
#include <hip/hip_bf16.h>

#define B_ 128
#define T_ 300
#define TC_ 20
#define DW_ 16
#define DC_ 32
#define UC_ 32
#define UM_ 64
#define POS_ 20
#define PAR_ 8
#define VW_ 1834
#define VC_ 132
#define DIN_ 76
#define XS_ 80
#define NROW (B_*T_)

__device__ __forceinline__ float fast_sig(float x){
  return __builtin_amdgcn_rcpf(1.f + __expf(-x));
}
__device__ __forceinline__ float fast_tanh(float x){
  return __builtin_amdgcn_rcpf(1.f + __expf(-2.f*x))*2.f - 1.f;
}

// ---- prep: xzc[v][j] = sum_k emb_char[v][k]*char_Wx[k][j] + char_b[j]  (132 x 128)
__global__ void k_xzc(const float* __restrict__ emb_char, const float* __restrict__ Wx,
                      const float* __restrict__ bias, float* __restrict__ xzc){
  int v = blockIdx.x, j = threadIdx.x;
  float acc = bias[j];
  #pragma unroll
  for (int k=0;k<DC_;k++) acc += emb_char[v*DC_+k]*Wx[k*(4*UC_)+j];
  xzc[v*(4*UC_)+j] = acc;
}

// ---- prep: WhT[j][k] = char_Wh[k][j]   (128 x 32)
__global__ void k_trans(const float* __restrict__ Wh, float* __restrict__ WhT){
  int t = blockIdx.x*256 + threadIdx.x;   // 4096
  int j = t >> 5, k = t & 31;
  WhT[t] = Wh[k*(4*UC_)+j];
}

// ---- fill x cols [0..16) = word emb, [48..68) = pos, [68..76) = par
__global__ void k_xfill(const int* __restrict__ word_in, const float* __restrict__ emb_wor,
                        const float* __restrict__ pos, const float* __restrict__ par,
                        float* __restrict__ x){
  int r = blockIdx.x*4 + threadIdx.x/80;
  int c = threadIdx.x%80;
  float v;
  if (c < DW_)                     v = emb_wor[word_in[r]*DW_ + c];
  else if (c < DW_+UC_)            return;             // char kernel fills
  else if (c < DW_+UC_+POS_)       v = pos[r*POS_ + (c-(DW_+UC_))];
  else if (c < DIN_)               v = par[r*PAR_ + (c-(DW_+UC_+POS_))];
  else                             return;             // pad, never read
  x[r*XS_ + c] = v;
}

// ---- char LSTM: block = 64 sequences x 4 waves (wave w owns units w*8..w*8+7)
__global__ __launch_bounds__(256) void k_char(const int* __restrict__ char_in,
        const float* __restrict__ xzc, const float* __restrict__ WhT,
        float* __restrict__ x){
  __shared__ float hbuf[2][64][33];
  const int lane = threadIdx.x & 63;
  const int w = __builtin_amdgcn_readfirstlane(threadIdx.x >> 6);
  const int u0 = w*8;
  const int seq = blockIdx.x*64 + lane;

  float c[8], ho[8];
  #pragma unroll
  for (int i=0;i<8;i++){ c[i]=0.f; ho[i]=0.f; hbuf[0][lane][u0+i]=0.f; }
  __syncthreads();

  for (int t=0;t<TC_;t++){
    int idx = char_in[seq*TC_ + t];
    bool m = (idx != 0);
    // gather xz row slice for this wave's units, all 4 gates
    float zxf[32];
    const float4* xz4 = reinterpret_cast<const float4*>(xzc + idx*(4*UC_) + u0);
    #pragma unroll
    for (int g=0; g<4; g++){
      float4 a = xz4[g*8];
      float4 bq = xz4[g*8+1];
      zxf[g*8+0]=a.x;  zxf[g*8+1]=a.y;  zxf[g*8+2]=a.z;  zxf[g*8+3]=a.w;
      zxf[g*8+4]=bq.x; zxf[g*8+5]=bq.y; zxf[g*8+6]=bq.z; zxf[g*8+7]=bq.w;
    }
    // full h of my sequence
    float hf[32];
    #pragma unroll
    for (int k=0;k<32;k++) hf[k] = hbuf[t&1][lane][k];

    #pragma unroll
    for (int u=0;u<8;u++){
      float zi=0.f, zf=0.f, zg=0.f, zo=0.f;
      const float* wi = WhT + (0*UC_+u0+u)*32;
      const float* wf = WhT + (1*UC_+u0+u)*32;
      const float* wg = WhT + (2*UC_+u0+u)*32;
      const float* wo = WhT + (3*UC_+u0+u)*32;
      #pragma unroll
      for (int k=0;k<32;k++){
        zi += hf[k]*wi[k]; zf += hf[k]*wf[k];
        zg += hf[k]*wg[k]; zo += hf[k]*wo[k];
      }
      zi += zxf[u]; zf += zxf[8+u]; zg += zxf[16+u]; zo += zxf[24+u];
      float cn = fast_sig(zf)*c[u] + fast_sig(zi)*fast_tanh(zg);
      float hn = fast_sig(zo)*fast_tanh(cn);
      c[u]  = m ? cn : c[u];
      ho[u] = m ? hn : ho[u];
    }
    #pragma unroll
    for (int i=0;i<8;i++) hbuf[(t+1)&1][lane][u0+i] = ho[i];
    __syncthreads();
  }
  #pragma unroll
  for (int i=0;i<8;i++) x[seq*XS_ + DW_ + u0 + i] = ho[i];
}

// ---- word LSTM: one block per (batch, dir); thread j owns gate column j
__global__ __launch_bounds__(256) void k_rnn(const float* __restrict__ x,
      const int* __restrict__ word_in,
      const float* __restrict__ Wx_f, const float* __restrict__ Wh_f, const float* __restrict__ b_f,
      const float* __restrict__ Wx_b, const float* __restrict__ Wh_b, const float* __restrict__ b_b,
      float* __restrict__ hcat){
  __shared__ float xbuf[2][XS_];
  __shared__ float zbuf[4*UM_];
  const int j = threadIdx.x;
  const int dir = blockIdx.x & 1;
  const int b = blockIdx.x >> 1;
  const float* Wx = dir ? Wx_b : Wx_f;
  const float* Wh = dir ? Wh_b : Wh_f;
  const float* bb = dir ? b_b : b_f;

  float wx[DIN_], wh[UM_];
  #pragma unroll
  for (int k=0;k<DIN_;k++) wx[k] = Wx[k*(4*UM_) + j];
  #pragma unroll
  for (int k=0;k<UM_;k++)  wh[k] = Wh[k*(4*UM_) + j];
  const float bj = bb[j];
  const int l = j & 63;
  float h = 0.f, cc = 0.f;

  int row0 = b*T_ + (dir ? (T_-1) : 0);
  if (j < DIN_) xbuf[0][j] = x[row0*XS_ + j];
  __syncthreads();

  for (int t=0;t<T_;t++){
    const int tt = dir ? (T_-1-t) : t;
    const int row = b*T_ + tt;
    const int nt = t+1;
    float xn = 0.f;
    if (nt < T_ && j < DIN_){
      int nrow = b*T_ + (dir ? (T_-1-nt) : nt);
      xn = x[nrow*XS_ + j];                     // prefetch next x row
    }
    const int mword = word_in[row];             // uniform -> s_load

    float z = bj;
    #pragma unroll
    for (int k=0;k<DIN_;k++) z += xbuf[t&1][k]*wx[k];
    #pragma unroll
    for (int k=0;k<UM_;k++){
      float hk = __int_as_float(__builtin_amdgcn_readlane(__float_as_int(h), k));
      z += hk*wh[k];
    }
    zbuf[j] = z;
    __syncthreads();

    float zi = zbuf[l], zf = zbuf[64+l], zg = zbuf[128+l], zo = zbuf[192+l];
    float cn = fast_sig(zf)*cc + fast_sig(zi)*fast_tanh(zg);
    float hn = fast_sig(zo)*fast_tanh(cn);
    if (mword != 0){ cc = cn; h = hn; }
    if (j < UM_) hcat[row*(2*UM_) + dir*UM_ + j] = h;
    if (nt < T_ && j < DIN_) xbuf[nt&1][j] = xn;
    __syncthreads();
  }
}

// ---- dense + softmax
__global__ void k_dense(const float* __restrict__ hcat, const float* __restrict__ W,
                        const float* __restrict__ bias, float* __restrict__ out){
  int r = blockIdx.x*256 + threadIdx.x;
  const float4* h4 = reinterpret_cast<const float4*>(hcat + r*(2*UM_));
  float a0=bias[0], a1=bias[1], a2=bias[2], a3=bias[3];
  #pragma unroll
  for (int k4=0;k4<32;k4++){
    float4 hv = h4[k4];
    float he[4] = {hv.x, hv.y, hv.z, hv.w};
    #pragma unroll
    for (int e=0;e<4;e++){
      int k = k4*4+e;
      a0 += he[e]*W[k*4+0]; a1 += he[e]*W[k*4+1];
      a2 += he[e]*W[k*4+2]; a3 += he[e]*W[k*4+3];
    }
  }
  float mx = fmaxf(fmaxf(a0,a1), fmaxf(a2,a3));
  float e0=__expf(a0-mx), e1=__expf(a1-mx), e2=__expf(a2-mx), e3=__expf(a3-mx);
  float s = __builtin_amdgcn_rcpf(e0+e1+e2+e3);
  out[r*4+0]=e0*s; out[r*4+1]=e1*s; out[r*4+2]=e2*s; out[r*4+3]=e3*s;
}

extern "C" void kernel_launch(void* const* d_in, const int* in_sizes, int n_in,
                              void* d_out, int out_size, void* d_ws, size_t ws_size,
                              hipStream_t stream) {
  const int*   word_in  = (const int*)  d_in[0];
  const int*   char_in  = (const int*)  d_in[1];
  const float* inp_pos  = (const float*)d_in[2];
  const float* inp_par  = (const float*)d_in[3];
  const float* emb_wor  = (const float*)d_in[4];
  const float* emb_char = (const float*)d_in[5];
  const float* char_Wx  = (const float*)d_in[6];
  const float* char_Wh  = (const float*)d_in[7];
  const float* char_b   = (const float*)d_in[8];
  const float* fwd_Wx   = (const float*)d_in[9];
  const float* fwd_Wh   = (const float*)d_in[10];
  const float* fwd_b    = (const float*)d_in[11];
  const float* bwd_Wx   = (const float*)d_in[12];
  const float* bwd_Wh   = (const float*)d_in[13];
  const float* bwd_b    = (const float*)d_in[14];
  const float* dense_W  = (const float*)d_in[15];
  const float* dense_b  = (const float*)d_in[16];
  float* out = (float*)d_out;

  float* xw   = (float*)d_ws;              // NROW*XS_
  float* hcat = xw + (size_t)NROW*XS_;     // NROW*128
  float* xzc  = hcat + (size_t)NROW*128;   // 132*128
  float* whT  = xzc + (size_t)VC_*128;     // 128*32

  k_xzc  <<<VC_, 4*UC_, 0, stream>>>(emb_char, char_Wx, char_b, xzc);
  k_trans<<<16, 256, 0, stream>>>(char_Wh, whT);
  k_xfill<<<NROW/4, 320, 0, stream>>>(word_in, emb_wor, inp_pos, inp_par, xw);
  k_char <<<NROW/64, 256, 0, stream>>>(char_in, xzc, whT, xw);
  k_rnn  <<<2*B_, 256, 0, stream>>>(xw, word_in, fwd_Wx, fwd_Wh, fwd_b,
                                    bwd_Wx, bwd_Wh, bwd_b, hcat);
  k_dense<<<NROW/256, 256, 0, stream>>>(hcat, dense_W, dense_b, out);
}

// Round 2
// 451.682 us; speedup vs baseline: 1.5138x; 1.5138x over previous
//
#include <hip/hip_runtime.h>
#include <hip/hip_bf16.h>

#define B_ 128
#define T_ 300
#define TC_ 20
#define DW_ 16
#define DC_ 32
#define UC_ 32
#define UM_ 64
#define POS_ 20
#define PAR_ 8
#define VW_ 1834
#define VC_ 132
#define DIN_ 76
#define XS_ 80
#define NROW (B_*T_)

__device__ __forceinline__ float fast_sig(float x){
  return __builtin_amdgcn_rcpf(1.f + __expf(-x));
}
__device__ __forceinline__ float fast_tanh(float x){
  return __builtin_amdgcn_rcpf(1.f + __expf(-2.f*x))*2.f - 1.f;
}
__device__ __forceinline__ float rl(float v, int k){
  return __int_as_float(__builtin_amdgcn_readlane(__float_as_int(v), k));
}

// ---- prep: xzc[v][j] = sum_k emb_char[v][k]*char_Wx[k][j] + char_b[j]  (132 x 128)
__global__ void k_xzc(const float* __restrict__ emb_char, const float* __restrict__ Wx,
                      const float* __restrict__ bias, float* __restrict__ xzc){
  int v = blockIdx.x, j = threadIdx.x;
  float acc = bias[j];
  #pragma unroll
  for (int k=0;k<DC_;k++) acc += emb_char[v*DC_+k]*Wx[k*(4*UC_)+j];
  xzc[v*(4*UC_)+j] = acc;
}

// ---- fill x cols [0..16) = word emb, [48..68) = pos, [68..76) = par
__global__ void k_xfill(const int* __restrict__ word_in, const float* __restrict__ emb_wor,
                        const float* __restrict__ pos, const float* __restrict__ par,
                        float* __restrict__ x){
  int r = blockIdx.x*4 + threadIdx.x/80;
  int c = threadIdx.x%80;
  float v;
  if (c < DW_)                     v = emb_wor[word_in[r]*DW_ + c];
  else if (c < DW_+UC_)            return;             // char kernel fills
  else if (c < DW_+UC_+POS_)       v = pos[r*POS_ + (c-(DW_+UC_))];
  else if (c < DIN_)               v = par[r*PAR_ + (c-(DW_+UC_+POS_))];
  else                             return;             // pad, never read
  x[r*XS_ + c] = v;
}

// ---- char LSTM: thread = (seq, unit). 8 seqs/block, 32 threads/seq.
// Weights in VGPRs (loaded once); h broadcast via ds_bpermute within wave.
__global__ __launch_bounds__(256) void k_char(const int* __restrict__ char_in,
        const float* __restrict__ xzc, const float* __restrict__ Wh,
        float* __restrict__ x){
  __shared__ int sidx[8*TC_];
  const int tid = threadIdx.x;
  const int lane = tid & 63;
  const int u = tid & 31;               // unit
  const int grp = tid >> 5;             // 0..7 seq group in block
  const int seq = blockIdx.x*8 + grp;

  if (tid < 8*TC_) sidx[tid] = char_in[blockIdx.x*(8*TC_) + tid];

  // wh[g][k] = Wh[k*128 + g*32 + u] : coalesced across u
  float wh[4][32];
  #pragma unroll
  for (int g=0; g<4; g++)
    #pragma unroll
    for (int k=0; k<32; k++)
      wh[g][k] = Wh[k*(4*UC_) + g*32 + u];

  __syncthreads();
  const int hb4 = (lane & 32) << 2;     // bpermute byte base of my seq's 32-group

  float h = 0.f, c = 0.f;
  int idx = sidx[grp*TC_ + 0];
  float zx[4];
  #pragma unroll
  for (int g=0; g<4; g++) zx[g] = xzc[idx*(4*UC_) + g*32 + u];

  for (int t=0; t<TC_; t++){
    int idxn = (t+1 < TC_) ? sidx[grp*TC_ + t+1] : 0;
    float nzx[4];
    #pragma unroll
    for (int g=0; g<4; g++) nzx[g] = xzc[idxn*(4*UC_) + g*32 + u];  // prefetch

    float zi = zx[0], zf = zx[1], zg = zx[2], zo = zx[3];
    int hbits = __float_as_int(h);
    #pragma unroll
    for (int k=0; k<32; k++){
      float hk = __int_as_float(__builtin_amdgcn_ds_bpermute(hb4 + 4*k, hbits));
      zi += hk*wh[0][k]; zf += hk*wh[1][k];
      zg += hk*wh[2][k]; zo += hk*wh[3][k];
    }
    float cn = fast_sig(zf)*c + fast_sig(zi)*fast_tanh(zg);
    float hn = fast_sig(zo)*fast_tanh(cn);
    bool m = (idx != 0);
    c = m ? cn : c;
    h = m ? hn : h;
    idx = idxn;
    #pragma unroll
    for (int g=0; g<4; g++) zx[g] = nzx[g];
  }
  x[seq*XS_ + DW_ + u] = h;
}

// ---- xz GEMM: xz[row][j] = x_row · Wx[:,j] + b[j], j<256 fwd, j>=256 bwd. bf16 out.
__global__ __launch_bounds__(512) void k_xz(const float* __restrict__ x,
      const float* __restrict__ Wx_f, const float* __restrict__ b_f,
      const float* __restrict__ Wx_b, const float* __restrict__ b_b,
      __hip_bfloat16* __restrict__ xz){
  __shared__ float xs[16*XS_];
  const int j = threadIdx.x;
  const int jj = j & 255;
  const bool bwd = (j >= 256);
  const float* Wx = bwd ? Wx_b : Wx_f;
  const float bj = bwd ? b_b[jj] : b_f[jj];

  float w[DIN_];
  #pragma unroll
  for (int k=0; k<DIN_; k++) w[k] = Wx[k*(4*UM_) + jj];

  const int rowbase = blockIdx.x*16;
  for (int i=j; i<16*XS_; i+=512) xs[i] = x[rowbase*XS_ + i];
  __syncthreads();

  for (int r=0; r<16; r++){
    const float4* xr = reinterpret_cast<const float4*>(&xs[r*XS_]);
    float a0=bj, a1=0.f, a2=0.f, a3=0.f;
    #pragma unroll
    for (int c4=0; c4<19; c4++){
      float4 v = xr[c4];
      a0 += v.x*w[4*c4+0]; a1 += v.y*w[4*c4+1];
      a2 += v.z*w[4*c4+2]; a3 += v.w*w[4*c4+3];
    }
    xz[(size_t)(rowbase+r)*512 + j] = __float2bfloat16((a0+a1)+(a2+a3));
  }
}

// ---- word LSTM: one block per (batch, dir); thread j owns gate column j.
// Only Wh in registers; xz streamed (prefetched). One barrier/step (dbuf zbuf).
__global__ __launch_bounds__(256) void k_rnn(const __hip_bfloat16* __restrict__ xz,
      const int* __restrict__ word_in,
      const float* __restrict__ Wh_f, const float* __restrict__ Wh_b,
      float* __restrict__ hcat){
  __shared__ float zbuf[2][4*UM_];
  const int j = threadIdx.x;
  const int dir = blockIdx.x & 1;
  const int b = blockIdx.x >> 1;
  const float* Wh = dir ? Wh_b : Wh_f;

  float wh[UM_];
  #pragma unroll
  for (int k=0;k<UM_;k++) wh[k] = Wh[k*(4*UM_) + j];
  const int l = j & 63;
  float h = 0.f, cc = 0.f;

  int row = b*T_ + (dir ? (T_-1) : 0);
  const int rstep = dir ? -1 : 1;
  float zx = __bfloat162float(xz[(size_t)row*512 + dir*256 + j]);
  int mw = word_in[row];

  for (int t=0;t<T_;t++){
    const int nrow = row + rstep;
    float zxn = 0.f; int mwn = 0;
    if (t+1 < T_){
      zxn = __bfloat162float(xz[(size_t)nrow*512 + dir*256 + j]);  // prefetch
      mwn = word_in[nrow];
    }
    float a0=0.f, a1=0.f, a2=0.f, a3=0.f;
    #pragma unroll
    for (int k=0;k<UM_;k+=4){
      a0 += rl(h,k+0)*wh[k+0];
      a1 += rl(h,k+1)*wh[k+1];
      a2 += rl(h,k+2)*wh[k+2];
      a3 += rl(h,k+3)*wh[k+3];
    }
    zbuf[t&1][j] = zx + ((a0+a1)+(a2+a3));
    __syncthreads();
    float zi = zbuf[t&1][l],     zf = zbuf[t&1][64+l];
    float zg = zbuf[t&1][128+l], zo = zbuf[t&1][192+l];
    float cn = fast_sig(zf)*cc + fast_sig(zi)*fast_tanh(zg);
    float hn = fast_sig(zo)*fast_tanh(cn);
    if (mw != 0){ cc = cn; h = hn; }
    if (j < UM_) hcat[(size_t)row*(2*UM_) + dir*UM_ + j] = h;
    row = nrow; zx = zxn; mw = mwn;
  }
}

// ---- dense + softmax
__global__ void k_dense(const float* __restrict__ hcat, const float* __restrict__ W,
                        const float* __restrict__ bias, float* __restrict__ out){
  int r = blockIdx.x*256 + threadIdx.x;
  const float4* h4 = reinterpret_cast<const float4*>(hcat + (size_t)r*(2*UM_));
  float a0=bias[0], a1=bias[1], a2=bias[2], a3=bias[3];
  #pragma unroll
  for (int k4=0;k4<32;k4++){
    float4 hv = h4[k4];
    float he[4] = {hv.x, hv.y, hv.z, hv.w};
    #pragma unroll
    for (int e=0;e<4;e++){
      int k = k4*4+e;
      a0 += he[e]*W[k*4+0]; a1 += he[e]*W[k*4+1];
      a2 += he[e]*W[k*4+2]; a3 += he[e]*W[k*4+3];
    }
  }
  float mx = fmaxf(fmaxf(a0,a1), fmaxf(a2,a3));
  float e0=__expf(a0-mx), e1=__expf(a1-mx), e2=__expf(a2-mx), e3=__expf(a3-mx);
  float s = __builtin_amdgcn_rcpf(e0+e1+e2+e3);
  out[r*4+0]=e0*s; out[r*4+1]=e1*s; out[r*4+2]=e2*s; out[r*4+3]=e3*s;
}

extern "C" void kernel_launch(void* const* d_in, const int* in_sizes, int n_in,
                              void* d_out, int out_size, void* d_ws, size_t ws_size,
                              hipStream_t stream) {
  const int*   word_in  = (const int*)  d_in[0];
  const int*   char_in  = (const int*)  d_in[1];
  const float* inp_pos  = (const float*)d_in[2];
  const float* inp_par  = (const float*)d_in[3];
  const float* emb_wor  = (const float*)d_in[4];
  const float* emb_char = (const float*)d_in[5];
  const float* char_Wx  = (const float*)d_in[6];
  const float* char_Wh  = (const float*)d_in[7];
  const float* char_b   = (const float*)d_in[8];
  const float* fwd_Wx   = (const float*)d_in[9];
  const float* fwd_Wh   = (const float*)d_in[10];
  const float* fwd_b    = (const float*)d_in[11];
  const float* bwd_Wx   = (const float*)d_in[12];
  const float* bwd_Wh   = (const float*)d_in[13];
  const float* bwd_b    = (const float*)d_in[14];
  const float* dense_W  = (const float*)d_in[15];
  const float* dense_b  = (const float*)d_in[16];
  float* out = (float*)d_out;

  float* xw   = (float*)d_ws;                      // NROW*XS_            f32
  float* hcat = xw + (size_t)NROW*XS_;             // NROW*128            f32
  float* xzc  = hcat + (size_t)NROW*128;           // 132*128             f32
  __hip_bfloat16* xzw = (__hip_bfloat16*)(xzc + (size_t)VC_*128);  // NROW*512 bf16

  k_xzc  <<<VC_, 4*UC_, 0, stream>>>(emb_char, char_Wx, char_b, xzc);
  k_xfill<<<NROW/4, 320, 0, stream>>>(word_in, emb_wor, inp_pos, inp_par, xw);
  k_char <<<NROW/8, 256, 0, stream>>>(char_in, xzc, char_Wh, xw);
  k_xz   <<<NROW/16, 512, 0, stream>>>(xw, fwd_Wx, fwd_b, bwd_Wx, bwd_b, xzw);
  k_rnn  <<<2*B_, 256, 0, stream>>>(xzw, word_in, fwd_Wh, bwd_Wh, hcat);
  k_dense<<<NROW/256, 256, 0, stream>>>(hcat, dense_W, dense_b, out);
}

// Round 3
// 435.987 us; speedup vs baseline: 1.5683x; 1.0360x over previous
//
#include <hip/hip_runtime.h>
#include <hip/hip_bf16.h>

#define B_ 128
#define T_ 300
#define TC_ 20
#define DW_ 16
#define DC_ 32
#define UC_ 32
#define UM_ 64
#define POS_ 20
#define PAR_ 8
#define VW_ 1834
#define VC_ 132
#define DIN_ 76
#define XS_ 80
#define NROW (B_*T_)

__device__ __forceinline__ float fast_sig(float x){
  return __builtin_amdgcn_rcpf(1.f + __expf(-x));
}
__device__ __forceinline__ float fast_tanh(float x){
  return __builtin_amdgcn_rcpf(1.f + __expf(-2.f*x))*2.f - 1.f;
}

// ---- prep: xzc[v][j] = sum_k emb_char[v][k]*char_Wx[k][j] + char_b[j]  (132 x 128)
__global__ void k_xzc(const float* __restrict__ emb_char, const float* __restrict__ Wx,
                      const float* __restrict__ bias, float* __restrict__ xzc){
  int v = blockIdx.x, j = threadIdx.x;
  float acc = bias[j];
  #pragma unroll
  for (int k=0;k<DC_;k++) acc += emb_char[v*DC_+k]*Wx[k*(4*UC_)+j];
  xzc[v*(4*UC_)+j] = acc;
}

// ---- fill x cols [0..16) = word emb, [48..68) = pos, [68..76) = par
__global__ void k_xfill(const int* __restrict__ word_in, const float* __restrict__ emb_wor,
                        const float* __restrict__ pos, const float* __restrict__ par,
                        float* __restrict__ x){
  int r = blockIdx.x*4 + threadIdx.x/80;
  int c = threadIdx.x%80;
  float v;
  if (c < DW_)                     v = emb_wor[word_in[r]*DW_ + c];
  else if (c < DW_+UC_)            return;             // char kernel fills
  else if (c < DW_+UC_+POS_)       v = pos[r*POS_ + (c-(DW_+UC_))];
  else if (c < DIN_)               v = par[r*PAR_ + (c-(DW_+UC_+POS_))];
  else                             return;             // pad, never read
  x[r*XS_ + c] = v;
}

// ---- char LSTM: thread = (seq, unit). 8 seqs/block, 32 threads/seq.
// wh[4][32] in VGPRs (launch_bounds(256,1) -> no spill); h exchanged via LDS
// within each 32-thread group (wave-synchronous, no barrier in step loop).
__global__ __launch_bounds__(256,1) void k_char(const int* __restrict__ char_in,
        const float* __restrict__ xzc, const float* __restrict__ Wh,
        float* __restrict__ x){
  __shared__ float hbuf[8][32];
  __shared__ int sidx[8*TC_];
  const int tid = threadIdx.x;
  const int u = tid & 31;               // unit
  const int grp = tid >> 5;             // 0..7 seq group in block
  const int seq = blockIdx.x*8 + grp;

  if (tid < 8*TC_) sidx[tid] = char_in[blockIdx.x*(8*TC_) + tid];
  hbuf[grp][u] = 0.f;

  // wh[g][k] = Wh[k*128 + g*32 + u] : coalesced across u
  float wh[4][32];
  #pragma unroll
  for (int g=0; g<4; g++)
    #pragma unroll
    for (int k=0; k<32; k++)
      wh[g][k] = Wh[k*(4*UC_) + g*32 + u];

  __syncthreads();

  float h = 0.f, c = 0.f;
  int idx = sidx[grp*TC_ + 0];
  float zx[4];
  #pragma unroll
  for (int g=0; g<4; g++) zx[g] = xzc[idx*(4*UC_) + g*32 + u];

  for (int t=0; t<TC_; t++){
    int idxn = (t+1 < TC_) ? sidx[grp*TC_ + t+1] : 0;
    float nzx[4];
    #pragma unroll
    for (int g=0; g<4; g++) nzx[g] = xzc[idxn*(4*UC_) + g*32 + u];  // prefetch

    float zi = zx[0], zf = zx[1], zg = zx[2], zo = zx[3];
    const float4* hb4 = reinterpret_cast<const float4*>(&hbuf[grp][0]);
    #pragma unroll
    for (int k4=0; k4<8; k4++){
      float4 hv = hb4[k4];
      float he[4] = {hv.x, hv.y, hv.z, hv.w};
      #pragma unroll
      for (int e=0; e<4; e++){
        int k = k4*4+e;
        zi += he[e]*wh[0][k]; zf += he[e]*wh[1][k];
        zg += he[e]*wh[2][k]; zo += he[e]*wh[3][k];
      }
    }
    float cn = fast_sig(zf)*c + fast_sig(zi)*fast_tanh(zg);
    float hn = fast_sig(zo)*fast_tanh(cn);
    bool m = (idx != 0);
    c = m ? cn : c;
    h = m ? hn : h;
    hbuf[grp][u] = h;                   // same-wave exchange, lgkmcnt-ordered
    idx = idxn;
    #pragma unroll
    for (int g=0; g<4; g++) zx[g] = nzx[g];
  }
  x[seq*XS_ + DW_ + u] = h;
}

// ---- xz GEMM: xz[row][j] = x_row · Wx[:,j] + b[j], j<256 fwd, j>=256 bwd. bf16 out.
__global__ __launch_bounds__(512,1) void k_xz(const float* __restrict__ x,
      const float* __restrict__ Wx_f, const float* __restrict__ b_f,
      const float* __restrict__ Wx_b, const float* __restrict__ b_b,
      __hip_bfloat16* __restrict__ xz){
  __shared__ float xs[16*XS_];
  const int j = threadIdx.x;
  const int jj = j & 255;
  const bool bwd = (j >= 256);
  const float* Wx = bwd ? Wx_b : Wx_f;
  const float bj = bwd ? b_b[jj] : b_f[jj];

  float w[DIN_];
  #pragma unroll
  for (int k=0; k<DIN_; k++) w[k] = Wx[k*(4*UM_) + jj];

  const int rowbase = blockIdx.x*16;
  for (int i=j; i<16*XS_; i+=512) xs[i] = x[rowbase*XS_ + i];
  __syncthreads();

  for (int r=0; r<16; r++){
    const float4* xr = reinterpret_cast<const float4*>(&xs[r*XS_]);
    float a0=bj, a1=0.f, a2=0.f, a3=0.f;
    #pragma unroll
    for (int c4=0; c4<19; c4++){
      float4 v = xr[c4];
      a0 += v.x*w[4*c4+0]; a1 += v.y*w[4*c4+1];
      a2 += v.z*w[4*c4+2]; a3 += v.w*w[4*c4+3];
    }
    xz[(size_t)(rowbase+r)*512 + j] = __float2bfloat16((a0+a1)+(a2+a3));
  }
}

// ---- word LSTM: one block per (batch, dir); thread j owns gate column j.
// h kept redundantly per-wave in LDS -> z-compute reads 16x ds_read_b128,
// no readlane chain. One barrier per step (dbuf zbuf; hbuf is within-wave).
__global__ __launch_bounds__(256,1) void k_rnn(const __hip_bfloat16* __restrict__ xz,
      const int* __restrict__ word_in,
      const float* __restrict__ Wh_f, const float* __restrict__ Wh_b,
      float* __restrict__ hcat){
  __shared__ float zbuf[2][4*UM_];
  __shared__ float hbuf[4][UM_];
  const int j = threadIdx.x;
  const int w = j >> 6;
  const int l = j & 63;
  const int dir = blockIdx.x & 1;
  const int b = blockIdx.x >> 1;
  const float* Wh = dir ? Wh_b : Wh_f;

  float wh[UM_];
  #pragma unroll
  for (int k=0;k<UM_;k++) wh[k] = Wh[k*(4*UM_) + j];
  float h = 0.f, cc = 0.f;
  hbuf[w][l] = 0.f;                     // per-wave copy, within-wave ordering

  int row = b*T_ + (dir ? (T_-1) : 0);
  const int rstep = dir ? -1 : 1;
  float zx = __bfloat162float(xz[(size_t)row*512 + dir*256 + j]);
  int mw = word_in[row];

  for (int t=0;t<T_;t++){
    const int nrow = row + rstep;
    float zxn = 0.f; int mwn = 0;
    if (t+1 < T_){
      zxn = __bfloat162float(xz[(size_t)nrow*512 + dir*256 + j]);  // prefetch
      mwn = word_in[nrow];
    }
    float z = zx;
    const float4* hb4 = reinterpret_cast<const float4*>(&hbuf[w][0]);
    #pragma unroll
    for (int k4=0;k4<16;k4++){
      float4 hv = hb4[k4];
      z += hv.x*wh[k4*4+0] + hv.y*wh[k4*4+1] + hv.z*wh[k4*4+2] + hv.w*wh[k4*4+3];
    }
    zbuf[t&1][j] = z;
    __syncthreads();
    float zi = zbuf[t&1][l],     zf = zbuf[t&1][64+l];
    float zg = zbuf[t&1][128+l], zo = zbuf[t&1][192+l];
    float cn = fast_sig(zf)*cc + fast_sig(zi)*fast_tanh(zg);
    float hn = fast_sig(zo)*fast_tanh(cn);
    if (mw != 0){ cc = cn; h = hn; }    // every wave updates all 64 units
    hbuf[w][l] = h;                     // within-wave, visible next step
    if (j < UM_) hcat[(size_t)row*(2*UM_) + dir*UM_ + j] = h;
    row = nrow; zx = zxn; mw = mwn;
  }
}

// ---- dense + softmax
__global__ void k_dense(const float* __restrict__ hcat, const float* __restrict__ W,
                        const float* __restrict__ bias, float* __restrict__ out){
  int r = blockIdx.x*256 + threadIdx.x;
  const float4* h4 = reinterpret_cast<const float4*>(hcat + (size_t)r*(2*UM_));
  float a0=bias[0], a1=bias[1], a2=bias[2], a3=bias[3];
  #pragma unroll
  for (int k4=0;k4<32;k4++){
    float4 hv = h4[k4];
    float he[4] = {hv.x, hv.y, hv.z, hv.w};
    #pragma unroll
    for (int e=0;e<4;e++){
      int k = k4*4+e;
      a0 += he[e]*W[k*4+0]; a1 += he[e]*W[k*4+1];
      a2 += he[e]*W[k*4+2]; a3 += he[e]*W[k*4+3];
    }
  }
  float mx = fmaxf(fmaxf(a0,a1), fmaxf(a2,a3));
  float e0=__expf(a0-mx), e1=__expf(a1-mx), e2=__expf(a2-mx), e3=__expf(a3-mx);
  float s = __builtin_amdgcn_rcpf(e0+e1+e2+e3);
  out[r*4+0]=e0*s; out[r*4+1]=e1*s; out[r*4+2]=e2*s; out[r*4+3]=e3*s;
}

extern "C" void kernel_launch(void* const* d_in, const int* in_sizes, int n_in,
                              void* d_out, int out_size, void* d_ws, size_t ws_size,
                              hipStream_t stream) {
  const int*   word_in  = (const int*)  d_in[0];
  const int*   char_in  = (const int*)  d_in[1];
  const float* inp_pos  = (const float*)d_in[2];
  const float* inp_par  = (const float*)d_in[3];
  const float* emb_wor  = (const float*)d_in[4];
  const float* emb_char = (const float*)d_in[5];
  const float* char_Wx  = (const float*)d_in[6];
  const float* char_Wh  = (const float*)d_in[7];
  const float* char_b   = (const float*)d_in[8];
  const float* fwd_Wx   = (const float*)d_in[9];
  const float* fwd_Wh   = (const float*)d_in[10];
  const float* fwd_b    = (const float*)d_in[11];
  const float* bwd_Wx   = (const float*)d_in[12];
  const float* bwd_Wh   = (const float*)d_in[13];
  const float* bwd_b    = (const float*)d_in[14];
  const float* dense_W  = (const float*)d_in[15];
  const float* dense_b  = (const float*)d_in[16];
  float* out = (float*)d_out;

  float* xw   = (float*)d_ws;                      // NROW*XS_            f32
  float* hcat = xw + (size_t)NROW*XS_;             // NROW*128            f32
  float* xzc  = hcat + (size_t)NROW*128;           // 132*128             f32
  __hip_bfloat16* xzw = (__hip_bfloat16*)(xzc + (size_t)VC_*128);  // NROW*512 bf16

  k_xzc  <<<VC_, 4*UC_, 0, stream>>>(emb_char, char_Wx, char_b, xzc);
  k_xfill<<<NROW/4, 320, 0, stream>>>(word_in, emb_wor, inp_pos, inp_par, xw);
  k_char <<<NROW/8, 256, 0, stream>>>(char_in, xzc, char_Wh, xw);
  k_xz   <<<NROW/16, 512, 0, stream>>>(xw, fwd_Wx, fwd_b, bwd_Wx, bwd_b, xzw);
  k_rnn  <<<2*B_, 256, 0, stream>>>(xzw, word_in, fwd_Wh, bwd_Wh, hcat);
  k_dense<<<NROW/256, 256, 0, stream>>>(hcat, dense_W, dense_b, out);
}